// Round 9
// baseline (151.224 us; speedup 1.0000x reference)
//
#include <hip/hip_runtime.h>
#include <math.h>

#define BB 1024
#define S 32
#define DIM 64
#define NREL 237
#define SIGMA 0.1f

// ---- workspace layout ----
// Wr stored as bf16 (ushort[238*64] = 30464 B) at byte offset 0.
// Float regions follow (float offsets into (float*)ws):
#define OFS_WC0   7616                    // 64*237 : W_agg1 @ W_out[:237]
#define N_WC      (64*237)
#define OFS_WC1   (OFS_WC0 + N_WC)        // 64*237 : W_agg1 @ W_out[237:]
#define OFS_BC    (OFS_WC1 + N_WC)        // 237
#define OFS_HC    (OFS_BC + 237)          // 64

// LDS map (float offsets), gather phase:
//   s_wr (bf16)  [0,7616)      238 rows x 64 ushort (128 B/row)
//   s_r2m (int)  [7616,8640)   32 j x 32 s
//   s_r1  (int)  [8640,8704)   2 units x 32
//   s_ent2(int)  [8704,8768)
//   s_m1         [8768,8832)
//   s_v1         [8832,11008)  32 x 68
//   s_ov         [11008,11136) 2 x 64 (persists into epilogue)
// epilogue aliases [0,1600):
//   s_ymix [0,240) | s_outv [240,480) | s_red [480,992) | s_h [992,1056)
//   s_omix [1056,1120) | s_vp [1120,1600)
// total 11136 floats = 44544 B -> 3 blocks/CU x 512 thr = 24 waves/CU.
#define LDS_BYTES 44544

__device__ __forceinline__ float selu_f(float x) {
    const float alpha = 1.6732632423543772f;
    const float scale = 1.0507009873554805f;
    return scale * (x > 0.f ? x : alpha * expm1f(x));
}

__device__ __forceinline__ unsigned short f2bf(float f) {
    unsigned int b = __float_as_uint(f);
    return (unsigned short)((b + 0x7fffu + ((b >> 16) & 1u)) >> 16);
}

// ---------- Kernel A: fold b-independent linear algebra ----------
__global__ __launch_bounds__(256) void precompute_kernel(
    const float* __restrict__ rel_feat, const float* __restrict__ W0,
    const float* __restrict__ W1, const float* __restrict__ b1,
    const float* __restrict__ W_out, const float* __restrict__ b_out,
    const float* __restrict__ mW1, const float* __restrict__ mb1,
    float* __restrict__ ws) {
    __shared__ float red[256];
    int blk = blockIdx.x;
    const int tid = threadIdx.x;

    if (blk < 60) {                        // Wr[r][o] -> bf16, 64-deep
        int idx = blk * 256 + tid;
        if (idx < 238 * 64) {
            int r = idx >> 6, o = idx & 63;
            float acc = 0.f;
            if (r < NREL) {
#pragma unroll 8
                for (int d = 0; d < 64; ++d)
                    acc += rel_feat[r * 64 + d] * W0[d * 64 + o];
            }
            ((unsigned short*)ws)[idx] = f2bf(acc);   // row 237 stays 0
        }
        return;
    }
    blk -= 60;
    if (blk < 512) {                       // Wc0 / Wc1 : 64x237 each, 237-deep
        int half = blk >> 8;
        int lb = blk & 255;
        int o = lb >> 2, ct = lb & 3;
        int cl = tid & 63, g = tid >> 6;
        int c = ct * 64 + cl;
        const float* Wsrc = W_out + half * 237 * 237;
        float acc = 0.f;
        if (c < NREL) {
            int k0 = g * 60, k1 = (g == 3) ? 237 : (k0 + 60);
#pragma unroll 4
            for (int k = k0; k < k1; ++k)
                acc += W1[o * 237 + k] * Wsrc[k * 237 + c];
        }
        red[tid] = acc;
        __syncthreads();
        if (g == 0 && c < NREL) {
            float s = red[cl] + red[64 + cl] + red[128 + cl] + red[192 + cl];
            ws[(half ? OFS_WC1 : OFS_WC0) + o * 237 + c] = s;
        }
        return;
    }
    blk -= 512;
    if (blk < 4) {                         // bc[c]
        int cl = tid & 63, g = tid >> 6;
        int c = blk * 64 + cl;
        float acc = 0.f;
        if (c < NREL) {
            int k0 = g * 60, k1 = (g == 3) ? 237 : (k0 + 60);
#pragma unroll 4
            for (int k = k0; k < k1; ++k)
                acc += b1[k] * (W_out[k * 237 + c] + W_out[(237 + k) * 237 + c]);
        }
        red[tid] = acc;
        __syncthreads();
        if (g == 0 && c < NREL)
            ws[OFS_BC + c] = b_out[c] + red[cl] + red[64 + cl] + red[128 + cl] + red[192 + cl];
        return;
    }
    // hc[w]
    {
        int w = tid & 63, g = tid >> 6;
        int k0 = g * 60, k1 = (g == 3) ? 237 : (k0 + 60);
        float acc = 0.f;
#pragma unroll 4
        for (int k = k0; k < k1; ++k)
            acc += b1[k] * mW1[k * 64 + w];
        red[tid] = acc;
        __syncthreads();
        if (g == 0)
            ws[OFS_HC + w] = mb1[w] + red[w] + red[64 + w] + red[128 + w] + red[192 + w];
    }
}

// bf16x4 unpack: uint2 holds 4 consecutive bf16 (elem i = bits<<16 of lane i)
#define BF_ACC(sum, d) {                                                  \
    sum.x += __uint_as_float((d).x << 16);                                \
    sum.y += __uint_as_float((d).x & 0xffff0000u);                        \
    sum.z += __uint_as_float((d).y << 16);                                \
    sum.w += __uint_as_float((d).y & 0xffff0000u); }

// ---------- Kernel GF: gather + epilogue fused, 1 b per block, 512 threads ----------
__global__ __launch_bounds__(512) void gf_kernel(
    const int* __restrict__ ep, const int* __restrict__ te_arr,
    const int* __restrict__ e2e_tab, const int* __restrict__ e2ent,
    const int* __restrict__ e2r, const float* __restrict__ b0,
    const float* __restrict__ t_arr, const float* __restrict__ eps,
    const float* __restrict__ W1, const float* __restrict__ mW1,
    const float* __restrict__ mW2, const float* __restrict__ mb2,
    const float* __restrict__ mW3, const float* __restrict__ mb3,
    const float* __restrict__ mW4, const float* __restrict__ mb4,
    const float* __restrict__ ws, float* __restrict__ out) {
    extern __shared__ float smem[];
    unsigned short* s_wr = (unsigned short*)smem;     // [0,7616) floats
    int*   s_r2m  = (int*)(smem + 7616);
    int*   s_r1   = (int*)(smem + 8640);
    int*   s_ent2 = (int*)(smem + 8704);
    float* s_m1   = smem + 8768;
    float* s_v1   = smem + 8832;
    float* s_ov   = smem + 11008;

    const int tid = threadIdx.x;
    const int b = blockIdx.x;
    const int c = tid & 15;
    const int te = te_arr[b];
    const float4 b0v = ((const float4*)b0)[c];

    // stage Wr (bf16, 30464 B) into LDS as uint4
    {
        const uint4* src = (const uint4*)ws;
        uint4* dst = (uint4*)s_wr;
        for (int i = tid; i < 1904; i += 512) dst[i] = src[i];
    }
    const uint2* W2 = (const uint2*)s_wr;   // row r, elem-group c at r*16+c

    // stage-1 for both sides
    if (tid < 64) {
        int u = tid >> 5, s = tid & 31;
        int ent = ep[b * 2 + u];
        int e1 = e2e_tab[ent * S + s];
        s_r1[u * 32 + s] = e2r[e1];
        s_m1[u * 32 + s] = (e1 != te) ? 1.0f : 0.0f;
        s_ent2[u * 32 + s] = e2ent[e1];
    }
    __syncthreads();

    // prologue: r2m for unit 0
    for (int p = tid; p < 1024; p += 512) {
        int j = p >> 5, s = p & 31;
        int e2 = e2e_tab[s_ent2[j] * S + s];
        s_r2m[p] = (e2 == te) ? NREL : e2r[e2];
    }
    __syncthreads();

    const float inv = 1.0f / 32.0f;
    for (int u = 0; u < 2; ++u) {
        {
            const int j = tid >> 4;        // 32 groups of 16 threads, one j each
            const int* rr = &s_r2m[j * 32];
            uint2 ds = W2[s_r1[u * 32 + j] * 16 + c];
            float4 self = make_float4(0.f, 0.f, 0.f, 0.f);
            BF_ACC(self, ds)
            float4 sa = make_float4(0.f, 0.f, 0.f, 0.f);
            float4 sb = make_float4(0.f, 0.f, 0.f, 0.f);
#pragma unroll
            for (int s = 0; s < 16; ++s) {
                uint2 d = W2[rr[s] * 16 + c];
                BF_ACC(sa, d)
            }
#pragma unroll
            for (int s = 16; s < 32; ++s) {
                uint2 d = W2[rr[s] * 16 + c];
                BF_ACC(sb, d)
            }
            float m = s_m1[u * 32 + j];
            float4 r;
            r.x = fmaxf(self.x + (sa.x + sb.x) * inv + b0v.x, 0.f) * m;
            r.y = fmaxf(self.y + (sa.y + sb.y) * inv + b0v.y, 0.f) * m;
            r.z = fmaxf(self.z + (sa.z + sb.z) * inv + b0v.z, 0.f) * m;
            r.w = fmaxf(self.w + (sa.w + sb.w) * inv + b0v.w, 0.f) * m;
            *((float4*)&s_v1[j * 68 + c * 4]) = r;
        }
        __syncthreads();
        if (tid < 64) {
            float sum = 0.f;
#pragma unroll 8
            for (int j = 0; j < 32; ++j) sum += s_v1[j * 68 + tid];
            s_ov[u * 64 + tid] = sum * inv;
        }
        if (u == 0) {
            for (int p = tid; p < 1024; p += 512) {
                int j = p >> 5, s = p & 31;
                int e2 = e2e_tab[s_ent2[32 + j] * S + s];
                s_r2m[p] = (e2 == te) ? NREL : e2r[e2];
            }
        }
        __syncthreads();
    }

    // ---------------- epilogue (aliases s_wr region; s_ov at 11008 safe) --------
    float* s_ymix = smem;          // 240
    float* s_outv = smem + 240;    // 240
    float* s_red  = smem + 480;    // 512
    float* s_h    = smem + 992;    // 64
    float* s_omix = smem + 1056;   // 64
    float* s_vp   = smem + 1120;   // 2*240
    const float tb = t_arr[b];
    const float* Wc0 = ws + OFS_WC0;
    const float* Wc1 = ws + OFS_WC1;
    const float* bc = ws + OFS_BC;
    const float* hc = ws + OFS_HC;

    if (tid < 64)
        s_omix[tid] = (1.f - tb) * s_ov[tid] + tb * s_ov[64 + tid];
    __syncthreads();

    // parallel halves: ymix (threads 0-255) and outv (threads 256-511)
    if (tid < 256) {
        if (tid < NREL) {
            float y = 0.f;
#pragma unroll 4
            for (int d = 0; d < 64; ++d)
                y += s_omix[d] * W1[d * 237 + tid];
            s_ymix[tid] = y;
        }
    } else {
        int cc = tid - 256;
        if (cc < NREL) {
            float a = bc[cc];
#pragma unroll 4
            for (int d = 0; d < 64; ++d)
                a += s_ov[d] * Wc0[d * 237 + cc] + s_ov[64 + d] * Wc1[d * 237 + cc];
            s_outv[cc] = a;
        }
    }
    __syncthreads();

    // h1: k-split 8 (512 = 64 x 8)
    {
        int w = tid & 63, q = tid >> 6;
        int k0 = q * 30, k1 = (q == 7) ? 237 : (k0 + 30);
        const float* e = eps + b * 237;
        float a = 0.f;
#pragma unroll 4
        for (int k = k0; k < k1; ++k)
            a += (SIGMA * e[k] + s_ymix[k]) * mW1[k * 64 + w];
        s_red[tid] = a;
    }
    __syncthreads();
    if (tid < 64) {
        float h = hc[tid] + tb * mW1[237 * 64 + tid];
#pragma unroll
        for (int q = 0; q < 8; ++q) h += s_red[q * 64 + tid];
        s_h[tid] = selu_f(h);
    }
    __syncthreads();

    // h2: d-split 8
    {
        int w = tid & 63, q = tid >> 6;
        float a = 0.f;
#pragma unroll
        for (int d = q * 8; d < q * 8 + 8; ++d)
            a += s_h[d] * mW2[d * 64 + w];
        s_red[tid] = a;
    }
    __syncthreads();
    if (tid < 64) {
        float v = mb2[tid];
#pragma unroll
        for (int q = 0; q < 8; ++q) v += s_red[q * 64 + tid];
        s_h[tid] = selu_f(v);
    }
    __syncthreads();

    // h3: d-split 8
    {
        int w = tid & 63, q = tid >> 6;
        float a = 0.f;
#pragma unroll
        for (int d = q * 8; d < q * 8 + 8; ++d)
            a += s_h[d] * mW3[d * 64 + w];
        s_red[tid] = a;
    }
    __syncthreads();
    if (tid < 64) {
        float v = mb3[tid];
#pragma unroll
        for (int q = 0; q < 8; ++q) v += s_red[q * 64 + tid];
        s_h[tid] = selu_f(v);
    }
    __syncthreads();

    // vt: k-split 2, then final product
    {
        int half = tid >> 8, cc = tid & 255;
        if (cc < NREL) {
            float a = 0.f;
#pragma unroll 4
            for (int w = half * 32; w < half * 32 + 32; ++w)
                a += s_h[w] * mW4[w * 237 + cc];
            s_vp[half * 240 + cc] = a;
        }
    }
    __syncthreads();
    if (tid < NREL)
        out[b * 237 + tid] = s_outv[tid] * (mb4[tid] + s_vp[tid] + s_vp[240 + tid]);
}

extern "C" void kernel_launch(void* const* d_in, const int* in_sizes, int n_in,
                              void* d_out, int out_size, void* d_ws, size_t ws_size,
                              hipStream_t stream) {
    const int* ep       = (const int*)d_in[0];
    const int* te       = (const int*)d_in[1];
    // d_in[2] = labels : dead code in the reference
    const int* e2e      = (const int*)d_in[3];
    const int* e2ent    = (const int*)d_in[4];
    const int* e2r      = (const int*)d_in[5];
    const float* t      = (const float*)d_in[6];
    const float* eps    = (const float*)d_in[7];
    const float* relf   = (const float*)d_in[8];
    const float* W0     = (const float*)d_in[9];
    const float* b0     = (const float*)d_in[10];
    const float* W1     = (const float*)d_in[11];
    const float* b1     = (const float*)d_in[12];
    const float* W_out  = (const float*)d_in[13];
    const float* b_out  = (const float*)d_in[14];
    const float* mW1    = (const float*)d_in[15];
    const float* mb1    = (const float*)d_in[16];
    const float* mW2    = (const float*)d_in[17];
    const float* mb2    = (const float*)d_in[18];
    const float* mW3    = (const float*)d_in[19];
    const float* mb3    = (const float*)d_in[20];
    const float* mW4    = (const float*)d_in[21];
    const float* mb4    = (const float*)d_in[22];
    float* ws  = (float*)d_ws;
    float* out = (float*)d_out;

    hipLaunchKernelGGL(precompute_kernel, dim3(577), dim3(256), 0, stream,
                       relf, W0, W1, b1, W_out, b_out, mW1, mb1, ws);
    hipLaunchKernelGGL(gf_kernel, dim3(BB), dim3(512), LDS_BYTES, stream,
                       ep, te, e2e, e2ent, e2r, b0,
                       t, eps, W1, mW1, mW2, mb2, mW3, mb3, mW4, mb4, ws, out);
}

// Round 10
// 142.117 us; speedup vs baseline: 1.0641x; 1.0641x over previous
//
#include <hip/hip_runtime.h>
#include <math.h>

#define BB 1024
#define S 32
#define DIM 64
#define NREL 237
#define NENT 14541
#define SIGMA 0.1f

// ---- workspace layout (float offsets) ----
#define OFS_WR    0                       // 238*64  : Wr = relf_ext @ W_agg0 (row 237 = 0)
#define N_WR      (238*64)
#define OFS_WC0   15232                   // 64*237  : W_agg1 @ W_out[:237]
#define N_WC      (64*237)
#define OFS_WC1   (OFS_WC0 + N_WC)        // 64*237
#define OFS_BC    (OFS_WC1 + N_WC)        // 237
#define OFS_HC    (OFS_BC + 237)          // 64
#define OFS_A     45872                   // 14542*64 : per-entity aggregate (float4-aligned)

// gf LDS map (floats):
//   s_v1   [0,4352)      2 units x 32 j x 68
//   s_r1   [4352,4416)   int
//   s_ent2 [4416,4480)   int
//   s_m1   [4480,4544)
//   s_ov   [4544,4672)   2 x 64 (persists into epilogue)
// epilogue aliases [0,1600): s_ymix[0,240) s_outv[240,480) s_red[480,992)
//   s_h[992,1056) s_omix[1056,1120) s_vp[1120,1600)
// total 4672 floats = 18688 B -> LDS allows >4 blocks/CU; wave cap gives
// 4 blocks x 8 waves = 32 waves/CU (max occupancy).
#define LDS_BYTES 18688

__device__ __forceinline__ float selu_f(float x) {
    const float alpha = 1.6732632423543772f;
    const float scale = 1.0507009873554805f;
    return scale * (x > 0.f ? x : alpha * expm1f(x));
}

// ---------- Kernel A: fold b-independent linear algebra (R8 verbatim) ----------
__global__ __launch_bounds__(256) void precompute_kernel(
    const float* __restrict__ rel_feat, const float* __restrict__ W0,
    const float* __restrict__ W1, const float* __restrict__ b1,
    const float* __restrict__ W_out, const float* __restrict__ b_out,
    const float* __restrict__ mW1, const float* __restrict__ mb1,
    float* __restrict__ ws) {
    __shared__ float red[256];
    int blk = blockIdx.x;
    const int tid = threadIdx.x;

    if (blk < 60) {                        // Wr[r][o], 64-deep
        int idx = blk * 256 + tid;
        if (idx < 238 * 64) {
            int r = idx >> 6, o = idx & 63;
            float acc = 0.f;
            if (r < NREL) {
#pragma unroll 8
                for (int d = 0; d < 64; ++d)
                    acc += rel_feat[r * 64 + d] * W0[d * 64 + o];
            }
            ws[OFS_WR + idx] = acc;        // row 237 stays 0
        }
        return;
    }
    blk -= 60;
    if (blk < 512) {                       // Wc0 / Wc1 : 64x237 each, 237-deep
        int half = blk >> 8;
        int lb = blk & 255;
        int o = lb >> 2, ct = lb & 3;
        int cl = tid & 63, g = tid >> 6;
        int c = ct * 64 + cl;
        const float* Wsrc = W_out + half * 237 * 237;
        float acc = 0.f;
        if (c < NREL) {
            int k0 = g * 60, k1 = (g == 3) ? 237 : (k0 + 60);
#pragma unroll 4
            for (int k = k0; k < k1; ++k)
                acc += W1[o * 237 + k] * Wsrc[k * 237 + c];
        }
        red[tid] = acc;
        __syncthreads();
        if (g == 0 && c < NREL) {
            float s = red[cl] + red[64 + cl] + red[128 + cl] + red[192 + cl];
            ws[(half ? OFS_WC1 : OFS_WC0) + o * 237 + c] = s;
        }
        return;
    }
    blk -= 512;
    if (blk < 4) {                         // bc[c]
        int cl = tid & 63, g = tid >> 6;
        int c = blk * 64 + cl;
        float acc = 0.f;
        if (c < NREL) {
            int k0 = g * 60, k1 = (g == 3) ? 237 : (k0 + 60);
#pragma unroll 4
            for (int k = k0; k < k1; ++k)
                acc += b1[k] * (W_out[k * 237 + c] + W_out[(237 + k) * 237 + c]);
        }
        red[tid] = acc;
        __syncthreads();
        if (g == 0 && c < NREL)
            ws[OFS_BC + c] = b_out[c] + red[cl] + red[64 + cl] + red[128 + cl] + red[192 + cl];
        return;
    }
    // hc[w]
    {
        int w = tid & 63, g = tid >> 6;
        int k0 = g * 60, k1 = (g == 3) ? 237 : (k0 + 60);
        float acc = 0.f;
#pragma unroll 4
        for (int k = k0; k < k1; ++k)
            acc += b1[k] * mW1[k * 64 + w];
        red[tid] = acc;
        __syncthreads();
        if (g == 0)
            ws[OFS_HC + w] = mb1[w] + red[w] + red[64 + w] + red[128 + w] + red[192 + w];
    }
}

// ---------- Kernel B: per-entity aggregate A[ent] = Σ_s Wr[e2r[e2e[ent,s]]] ----------
// 16 entities per 256-thr block; tiny LDS -> full occupancy; L2-resident gathers.
__global__ __launch_bounds__(256) void agg_kernel(
    const int* __restrict__ e2e_tab, const int* __restrict__ e2r,
    float* __restrict__ ws) {
    __shared__ int s_r[512];               // 16 groups x 32
    const int tid = threadIdx.x;
    const int grp = tid >> 4, c = tid & 15;
    const int ent = blockIdx.x * 16 + grp;
    const bool ok = ent < (NENT + 1);
    if (ok) {
        int ea = e2e_tab[ent * S + c];
        int eb = e2e_tab[ent * S + 16 + c];
        s_r[grp * 32 + c] = e2r[ea];
        s_r[grp * 32 + 16 + c] = e2r[eb];
    }
    __syncthreads();
    if (ok) {
        const float4* Wr4 = (const float4*)(ws + OFS_WR);
        const int* rr = &s_r[grp * 32];
        float4 acc = make_float4(0.f, 0.f, 0.f, 0.f);
#pragma unroll
        for (int s = 0; s < 32; ++s) {
            float4 v = Wr4[rr[s] * 16 + c];
            acc.x += v.x; acc.y += v.y; acc.z += v.z; acc.w += v.w;
        }
        ((float4*)(ws + OFS_A))[ent * 16 + c] = acc;
    }
}

// ---------- Kernel GF: gather-from-A + epilogue, 1 b per block, 512 threads ----------
__global__ __launch_bounds__(512, 8) void gf_kernel(
    const int* __restrict__ ep, const int* __restrict__ te_arr,
    const int* __restrict__ e2e_tab, const int* __restrict__ e2ent,
    const int* __restrict__ e2r, const float* __restrict__ b0,
    const float* __restrict__ t_arr, const float* __restrict__ eps,
    const float* __restrict__ W1, const float* __restrict__ mW1,
    const float* __restrict__ mW2, const float* __restrict__ mb2,
    const float* __restrict__ mW3, const float* __restrict__ mb3,
    const float* __restrict__ mW4, const float* __restrict__ mb4,
    const float* __restrict__ ws, float* __restrict__ out) {
    extern __shared__ float smem[];
    float* s_v1   = smem;                  // 2*32*68
    int*   s_r1   = (int*)(smem + 4352);
    int*   s_ent2 = (int*)(smem + 4416);
    float* s_m1   = smem + 4480;
    float* s_ov   = smem + 4544;

    const int tid = threadIdx.x;
    const int b = blockIdx.x;
    const int grp = tid >> 4;              // 32 groups of 16 threads
    const int c = tid & 15;
    const int te = te_arr[b];
    const int rte = e2r[te];
    const float4* Wr4 = (const float4*)(ws + OFS_WR);
    const float4* A4  = (const float4*)(ws + OFS_A);
    const float4 b0v  = ((const float4*)b0)[c];
    const float4 wrte = Wr4[rte * 16 + c];

    // stage-1 for both sides
    if (tid < 64) {
        int u = tid >> 5, s = tid & 31;
        int ent = ep[b * 2 + u];
        int e1 = e2e_tab[ent * S + s];
        s_r1[u * 32 + s] = e2r[e1];
        s_m1[u * 32 + s] = (e1 != te) ? 1.0f : 0.0f;
        s_ent2[u * 32 + s] = e2ent[e1];
    }
    __syncthreads();

    const float inv = 1.0f / 32.0f;
    // both units, one barrier: group 'grp' owns j=grp for u=0 and u=1
#pragma unroll
    for (int u = 0; u < 2; ++u) {
        const int j = grp;
        const int ent2 = s_ent2[u * 32 + j];
        // mask-hit count for this j via 2 int loads/thread + 16-lane shfl reduce
        int e2a = e2e_tab[ent2 * S + c];
        int e2b = e2e_tab[ent2 * S + 16 + c];
        int cnt = (e2a == te) + (e2b == te);
        cnt += __shfl_xor(cnt, 1);
        cnt += __shfl_xor(cnt, 2);
        cnt += __shfl_xor(cnt, 4);
        cnt += __shfl_xor(cnt, 8);
        float4 a4   = A4[ent2 * 16 + c];
        float4 self = Wr4[s_r1[u * 32 + j] * 16 + c];
        float fc = (float)cnt;
        float m = s_m1[u * 32 + j];
        float4 r;
        r.x = fmaxf(self.x + (a4.x - fc * wrte.x) * inv + b0v.x, 0.f) * m;
        r.y = fmaxf(self.y + (a4.y - fc * wrte.y) * inv + b0v.y, 0.f) * m;
        r.z = fmaxf(self.z + (a4.z - fc * wrte.z) * inv + b0v.z, 0.f) * m;
        r.w = fmaxf(self.w + (a4.w - fc * wrte.w) * inv + b0v.w, 0.f) * m;
        *((float4*)&s_v1[(u * 32 + j) * 68 + c * 4]) = r;
    }
    __syncthreads();
    if (tid < 128) {
        int u = tid >> 6, w = tid & 63;
        float sum = 0.f;
#pragma unroll 8
        for (int j = 0; j < 32; ++j) sum += s_v1[(u * 32 + j) * 68 + w];
        s_ov[u * 64 + w] = sum * inv;
    }
    __syncthreads();

    // ---------------- epilogue (R9 structure; s_ov at 4544 safe) ----------------
    float* s_ymix = smem;          // 240
    float* s_outv = smem + 240;    // 240
    float* s_red  = smem + 480;    // 512
    float* s_h    = smem + 992;    // 64
    float* s_omix = smem + 1056;   // 64
    float* s_vp   = smem + 1120;   // 2*240
    const float tb = t_arr[b];
    const float* Wc0 = ws + OFS_WC0;
    const float* Wc1 = ws + OFS_WC1;
    const float* bc = ws + OFS_BC;
    const float* hc = ws + OFS_HC;

    if (tid < 64)
        s_omix[tid] = (1.f - tb) * s_ov[tid] + tb * s_ov[64 + tid];
    __syncthreads();

    // parallel halves: ymix (threads 0-255) and outv (threads 256-511)
    if (tid < 256) {
        if (tid < NREL) {
            float y = 0.f;
#pragma unroll 4
            for (int d = 0; d < 64; ++d)
                y += s_omix[d] * W1[d * 237 + tid];
            s_ymix[tid] = y;
        }
    } else {
        int cc = tid - 256;
        if (cc < NREL) {
            float a = bc[cc];
#pragma unroll 4
            for (int d = 0; d < 64; ++d)
                a += s_ov[d] * Wc0[d * 237 + cc] + s_ov[64 + d] * Wc1[d * 237 + cc];
            s_outv[cc] = a;
        }
    }
    __syncthreads();

    // h1: k-split 8 (512 = 64 x 8)
    {
        int w = tid & 63, q = tid >> 6;
        int k0 = q * 30, k1 = (q == 7) ? 237 : (k0 + 30);
        const float* e = eps + b * 237;
        float a = 0.f;
#pragma unroll 4
        for (int k = k0; k < k1; ++k)
            a += (SIGMA * e[k] + s_ymix[k]) * mW1[k * 64 + w];
        s_red[tid] = a;
    }
    __syncthreads();
    if (tid < 64) {
        float h = hc[tid] + tb * mW1[237 * 64 + tid];
#pragma unroll
        for (int q = 0; q < 8; ++q) h += s_red[q * 64 + tid];
        s_h[tid] = selu_f(h);
    }
    __syncthreads();

    // h2: d-split 8
    {
        int w = tid & 63, q = tid >> 6;
        float a = 0.f;
#pragma unroll
        for (int d = q * 8; d < q * 8 + 8; ++d)
            a += s_h[d] * mW2[d * 64 + w];
        s_red[tid] = a;
    }
    __syncthreads();
    if (tid < 64) {
        float v = mb2[tid];
#pragma unroll
        for (int q = 0; q < 8; ++q) v += s_red[q * 64 + tid];
        s_h[tid] = selu_f(v);
    }
    __syncthreads();

    // h3: d-split 8
    {
        int w = tid & 63, q = tid >> 6;
        float a = 0.f;
#pragma unroll
        for (int d = q * 8; d < q * 8 + 8; ++d)
            a += s_h[d] * mW3[d * 64 + w];
        s_red[tid] = a;
    }
    __syncthreads();
    if (tid < 64) {
        float v = mb3[tid];
#pragma unroll
        for (int q = 0; q < 8; ++q) v += s_red[q * 64 + tid];
        s_h[tid] = selu_f(v);
    }
    __syncthreads();

    // vt: k-split 2, then final product
    {
        int half = tid >> 8, cc = tid & 255;
        if (cc < NREL) {
            float a = 0.f;
#pragma unroll 4
            for (int w = half * 32; w < half * 32 + 32; ++w)
                a += s_h[w] * mW4[w * 237 + cc];
            s_vp[half * 240 + cc] = a;
        }
    }
    __syncthreads();
    if (tid < NREL)
        out[b * 237 + tid] = s_outv[tid] * (mb4[tid] + s_vp[tid] + s_vp[240 + tid]);
}

extern "C" void kernel_launch(void* const* d_in, const int* in_sizes, int n_in,
                              void* d_out, int out_size, void* d_ws, size_t ws_size,
                              hipStream_t stream) {
    const int* ep       = (const int*)d_in[0];
    const int* te       = (const int*)d_in[1];
    // d_in[2] = labels : dead code in the reference
    const int* e2e      = (const int*)d_in[3];
    const int* e2ent    = (const int*)d_in[4];
    const int* e2r      = (const int*)d_in[5];
    const float* t      = (const float*)d_in[6];
    const float* eps    = (const float*)d_in[7];
    const float* relf   = (const float*)d_in[8];
    const float* W0     = (const float*)d_in[9];
    const float* b0     = (const float*)d_in[10];
    const float* W1     = (const float*)d_in[11];
    const float* b1     = (const float*)d_in[12];
    const float* W_out  = (const float*)d_in[13];
    const float* b_out  = (const float*)d_in[14];
    const float* mW1    = (const float*)d_in[15];
    const float* mb1    = (const float*)d_in[16];
    const float* mW2    = (const float*)d_in[17];
    const float* mb2    = (const float*)d_in[18];
    const float* mW3    = (const float*)d_in[19];
    const float* mb3    = (const float*)d_in[20];
    const float* mW4    = (const float*)d_in[21];
    const float* mb4    = (const float*)d_in[22];
    float* ws  = (float*)d_ws;
    float* out = (float*)d_out;

    hipLaunchKernelGGL(precompute_kernel, dim3(577), dim3(256), 0, stream,
                       relf, W0, W1, b1, W_out, b_out, mW1, mb1, ws);
    hipLaunchKernelGGL(agg_kernel, dim3((NENT + 1 + 15) / 16), dim3(256), 0, stream,
                       e2e, e2r, ws);
    hipLaunchKernelGGL(gf_kernel, dim3(BB), dim3(512), LDS_BYTES, stream,
                       ep, te, e2e, e2ent, e2r, b0,
                       t, eps, W1, mW1, mW2, mb2, mW3, mb3, mW4, mb4, ws, out);
}

// Round 11
// 142.034 us; speedup vs baseline: 1.0647x; 1.0006x over previous
//
#include <hip/hip_runtime.h>
#include <math.h>

#define BB 1024
#define S 32
#define DIM 64
#define NREL 237
#define NENT 14541
#define SIGMA 0.1f

// ---- workspace layout (float offsets) ----
#define OFS_WR    0                       // 238*64  : Wr = relf_ext @ W_agg0 (row 237 = 0)
#define N_WR      (238*64)
#define OFS_WC0   15232                   // 64*237  : W_agg1 @ W_out[:237]
#define N_WC      (64*237)
#define OFS_WC1   (OFS_WC0 + N_WC)        // 64*237
#define OFS_BC    (OFS_WC1 + N_WC)        // 237
#define OFS_HC    (OFS_BC + 237)         // 64
#define OFS_A     45872                   // 14542*64 : per-entity aggregate (float4-aligned)

// gf LDS map (floats): unchanged from R10.
#define LDS_BYTES 18688

__device__ __forceinline__ float selu_f(float x) {
    const float alpha = 1.6732632423543772f;
    const float scale = 1.0507009873554805f;
    return scale * (x > 0.f ? x : alpha * expm1f(x));
}

// ---------- Kernel 1: Wr only (everything downstream depends on this) ----------
__global__ __launch_bounds__(256) void pre_wr_kernel(
    const float* __restrict__ rel_feat, const float* __restrict__ W0,
    float* __restrict__ ws) {
    int idx = blockIdx.x * 256 + threadIdx.x;
    if (idx < 238 * 64) {
        int r = idx >> 6, o = idx & 63;
        float acc = 0.f;
        if (r < NREL) {
#pragma unroll 8
            for (int d = 0; d < 64; ++d)
                acc += rel_feat[r * 64 + d] * W0[d * 64 + o];
        }
        ws[OFS_WR + idx] = acc;            // row 237 stays 0
    }
}

// ---------- Kernel 2 (fused): agg (L2-gather-bound) + Wc/bc/hc (FMA-bound) ----------
// The two workloads are independent (both depend only on Wr / raw inputs) and
// co-schedule on the same CUs: latency of one hides under compute of the other.
__global__ __launch_bounds__(512) void mid_kernel(
    const int* __restrict__ e2e_tab, const int* __restrict__ e2r,
    const float* __restrict__ W1, const float* __restrict__ b1,
    const float* __restrict__ W_out, const float* __restrict__ b_out,
    const float* __restrict__ mW1, const float* __restrict__ mb1,
    float* __restrict__ ws) {
    __shared__ int   s_r[1024];
    __shared__ float red[512];
    int blk = blockIdx.x;
    const int tid = threadIdx.x;

    if (blk < 455) {                       // agg: 32 entities per block
        const int grp = tid >> 4, c = tid & 15;
        const int ent = blk * 32 + grp;
        const bool ok = ent < (NENT + 1);
        if (ok) {
            int ea = e2e_tab[ent * S + c];
            int eb = e2e_tab[ent * S + 16 + c];
            s_r[grp * 32 + c] = e2r[ea];
            s_r[grp * 32 + 16 + c] = e2r[eb];
        }
        __syncthreads();
        if (ok) {
            const float4* Wr4 = (const float4*)(ws + OFS_WR);
            const int* rr = &s_r[grp * 32];
            float4 acc = make_float4(0.f, 0.f, 0.f, 0.f);
#pragma unroll
            for (int s = 0; s < 32; ++s) {
                float4 v = Wr4[rr[s] * 16 + c];
                acc.x += v.x; acc.y += v.y; acc.z += v.z; acc.w += v.w;
            }
            ((float4*)(ws + OFS_A))[ent * 16 + c] = acc;
        }
        return;
    }
    blk -= 455;
    if (blk < 512) {                       // Wc0/Wc1: 8-way k-split (chain ~30)
        int half = blk >> 8;
        int lb = blk & 255;
        int o = lb >> 2, ct = lb & 3;
        int cl = tid & 63, q = tid >> 6;
        int c = ct * 64 + cl;
        const float* Wsrc = W_out + half * 237 * 237;
        float acc = 0.f;
        if (c < NREL) {
            int k0 = q * 30, k1 = (q == 7) ? 237 : (k0 + 30);
#pragma unroll 4
            for (int k = k0; k < k1; ++k)
                acc += W1[o * 237 + k] * Wsrc[k * 237 + c];
        }
        red[tid] = acc;
        __syncthreads();
        if (q == 0 && c < NREL) {
            float s = 0.f;
#pragma unroll
            for (int qq = 0; qq < 8; ++qq) s += red[qq * 64 + cl];
            ws[(half ? OFS_WC1 : OFS_WC0) + o * 237 + c] = s;
        }
        return;
    }
    blk -= 512;
    if (blk < 4) {                         // bc[c]
        int cl = tid & 63, q = tid >> 6;
        int c = blk * 64 + cl;
        float acc = 0.f;
        if (c < NREL) {
            int k0 = q * 30, k1 = (q == 7) ? 237 : (k0 + 30);
#pragma unroll 4
            for (int k = k0; k < k1; ++k)
                acc += b1[k] * (W_out[k * 237 + c] + W_out[(237 + k) * 237 + c]);
        }
        red[tid] = acc;
        __syncthreads();
        if (q == 0 && c < NREL) {
            float s = b_out[c];
#pragma unroll
            for (int qq = 0; qq < 8; ++qq) s += red[qq * 64 + cl];
            ws[OFS_BC + c] = s;
        }
        return;
    }
    // hc[w]
    {
        int w = tid & 63, q = tid >> 6;
        int k0 = q * 30, k1 = (q == 7) ? 237 : (k0 + 30);
        float acc = 0.f;
#pragma unroll 4
        for (int k = k0; k < k1; ++k)
            acc += b1[k] * mW1[k * 64 + w];
        red[tid] = acc;
        __syncthreads();
        if (q == 0) {
            float s = mb1[w];
#pragma unroll
            for (int qq = 0; qq < 8; ++qq) s += red[qq * 64 + w];
            ws[OFS_HC + w] = s;
        }
    }
}

// ---------- Kernel GF: gather-from-A + epilogue (R10 verbatim) ----------
__global__ __launch_bounds__(512, 8) void gf_kernel(
    const int* __restrict__ ep, const int* __restrict__ te_arr,
    const int* __restrict__ e2e_tab, const int* __restrict__ e2ent,
    const int* __restrict__ e2r, const float* __restrict__ b0,
    const float* __restrict__ t_arr, const float* __restrict__ eps,
    const float* __restrict__ W1, const float* __restrict__ mW1,
    const float* __restrict__ mW2, const float* __restrict__ mb2,
    const float* __restrict__ mW3, const float* __restrict__ mb3,
    const float* __restrict__ mW4, const float* __restrict__ mb4,
    const float* __restrict__ ws, float* __restrict__ out) {
    extern __shared__ float smem[];
    float* s_v1   = smem;                  // 2*32*68
    int*   s_r1   = (int*)(smem + 4352);
    int*   s_ent2 = (int*)(smem + 4416);
    float* s_m1   = smem + 4480;
    float* s_ov   = smem + 4544;

    const int tid = threadIdx.x;
    const int b = blockIdx.x;
    const int grp = tid >> 4;              // 32 groups of 16 threads
    const int c = tid & 15;
    const int te = te_arr[b];
    const int rte = e2r[te];
    const float4* Wr4 = (const float4*)(ws + OFS_WR);
    const float4* A4  = (const float4*)(ws + OFS_A);
    const float4 b0v  = ((const float4*)b0)[c];
    const float4 wrte = Wr4[rte * 16 + c];

    // stage-1 for both sides
    if (tid < 64) {
        int u = tid >> 5, s = tid & 31;
        int ent = ep[b * 2 + u];
        int e1 = e2e_tab[ent * S + s];
        s_r1[u * 32 + s] = e2r[e1];
        s_m1[u * 32 + s] = (e1 != te) ? 1.0f : 0.0f;
        s_ent2[u * 32 + s] = e2ent[e1];
    }
    __syncthreads();

    const float inv = 1.0f / 32.0f;
#pragma unroll
    for (int u = 0; u < 2; ++u) {
        const int j = grp;
        const int ent2 = s_ent2[u * 32 + j];
        int e2a = e2e_tab[ent2 * S + c];
        int e2b = e2e_tab[ent2 * S + 16 + c];
        int cnt = (e2a == te) + (e2b == te);
        cnt += __shfl_xor(cnt, 1);
        cnt += __shfl_xor(cnt, 2);
        cnt += __shfl_xor(cnt, 4);
        cnt += __shfl_xor(cnt, 8);
        float4 a4   = A4[ent2 * 16 + c];
        float4 self = Wr4[s_r1[u * 32 + j] * 16 + c];
        float fc = (float)cnt;
        float m = s_m1[u * 32 + j];
        float4 r;
        r.x = fmaxf(self.x + (a4.x - fc * wrte.x) * inv + b0v.x, 0.f) * m;
        r.y = fmaxf(self.y + (a4.y - fc * wrte.y) * inv + b0v.y, 0.f) * m;
        r.z = fmaxf(self.z + (a4.z - fc * wrte.z) * inv + b0v.z, 0.f) * m;
        r.w = fmaxf(self.w + (a4.w - fc * wrte.w) * inv + b0v.w, 0.f) * m;
        *((float4*)&s_v1[(u * 32 + j) * 68 + c * 4]) = r;
    }
    __syncthreads();
    if (tid < 128) {
        int u = tid >> 6, w = tid & 63;
        float sum = 0.f;
#pragma unroll 8
        for (int j = 0; j < 32; ++j) sum += s_v1[(u * 32 + j) * 68 + w];
        s_ov[u * 64 + w] = sum * inv;
    }
    __syncthreads();

    // ---------------- epilogue ----------------
    float* s_ymix = smem;          // 240
    float* s_outv = smem + 240;    // 240
    float* s_red  = smem + 480;    // 512
    float* s_h    = smem + 992;    // 64
    float* s_omix = smem + 1056;   // 64
    float* s_vp   = smem + 1120;   // 2*240
    const float tb = t_arr[b];
    const float* Wc0 = ws + OFS_WC0;
    const float* Wc1 = ws + OFS_WC1;
    const float* bc = ws + OFS_BC;
    const float* hc = ws + OFS_HC;

    if (tid < 64)
        s_omix[tid] = (1.f - tb) * s_ov[tid] + tb * s_ov[64 + tid];
    __syncthreads();

    if (tid < 256) {
        if (tid < NREL) {
            float y = 0.f;
#pragma unroll 4
            for (int d = 0; d < 64; ++d)
                y += s_omix[d] * W1[d * 237 + tid];
            s_ymix[tid] = y;
        }
    } else {
        int cc = tid - 256;
        if (cc < NREL) {
            float a = bc[cc];
#pragma unroll 4
            for (int d = 0; d < 64; ++d)
                a += s_ov[d] * Wc0[d * 237 + cc] + s_ov[64 + d] * Wc1[d * 237 + cc];
            s_outv[cc] = a;
        }
    }
    __syncthreads();

    // h1: k-split 8
    {
        int w = tid & 63, q = tid >> 6;
        int k0 = q * 30, k1 = (q == 7) ? 237 : (k0 + 30);
        const float* e = eps + b * 237;
        float a = 0.f;
#pragma unroll 4
        for (int k = k0; k < k1; ++k)
            a += (SIGMA * e[k] + s_ymix[k]) * mW1[k * 64 + w];
        s_red[tid] = a;
    }
    __syncthreads();
    if (tid < 64) {
        float h = hc[tid] + tb * mW1[237 * 64 + tid];
#pragma unroll
        for (int q = 0; q < 8; ++q) h += s_red[q * 64 + tid];
        s_h[tid] = selu_f(h);
    }
    __syncthreads();

    // h2: d-split 8
    {
        int w = tid & 63, q = tid >> 6;
        float a = 0.f;
#pragma unroll
        for (int d = q * 8; d < q * 8 + 8; ++d)
            a += s_h[d] * mW2[d * 64 + w];
        s_red[tid] = a;
    }
    __syncthreads();
    if (tid < 64) {
        float v = mb2[tid];
#pragma unroll
        for (int q = 0; q < 8; ++q) v += s_red[q * 64 + tid];
        s_h[tid] = selu_f(v);
    }
    __syncthreads();

    // h3: d-split 8
    {
        int w = tid & 63, q = tid >> 6;
        float a = 0.f;
#pragma unroll
        for (int d = q * 8; d < q * 8 + 8; ++d)
            a += s_h[d] * mW3[d * 64 + w];
        s_red[tid] = a;
    }
    __syncthreads();
    if (tid < 64) {
        float v = mb3[tid];
#pragma unroll
        for (int q = 0; q < 8; ++q) v += s_red[q * 64 + tid];
        s_h[tid] = selu_f(v);
    }
    __syncthreads();

    // vt: k-split 2, then final product
    {
        int half = tid >> 8, cc = tid & 255;
        if (cc < NREL) {
            float a = 0.f;
#pragma unroll 4
            for (int w = half * 32; w < half * 32 + 32; ++w)
                a += s_h[w] * mW4[w * 237 + cc];
            s_vp[half * 240 + cc] = a;
        }
    }
    __syncthreads();
    if (tid < NREL)
        out[b * 237 + tid] = s_outv[tid] * (mb4[tid] + s_vp[tid] + s_vp[240 + tid]);
}

extern "C" void kernel_launch(void* const* d_in, const int* in_sizes, int n_in,
                              void* d_out, int out_size, void* d_ws, size_t ws_size,
                              hipStream_t stream) {
    const int* ep       = (const int*)d_in[0];
    const int* te       = (const int*)d_in[1];
    // d_in[2] = labels : dead code in the reference
    const int* e2e      = (const int*)d_in[3];
    const int* e2ent    = (const int*)d_in[4];
    const int* e2r      = (const int*)d_in[5];
    const float* t      = (const float*)d_in[6];
    const float* eps    = (const float*)d_in[7];
    const float* relf   = (const float*)d_in[8];
    const float* W0     = (const float*)d_in[9];
    const float* b0     = (const float*)d_in[10];
    const float* W1     = (const float*)d_in[11];
    const float* b1     = (const float*)d_in[12];
    const float* W_out  = (const float*)d_in[13];
    const float* b_out  = (const float*)d_in[14];
    const float* mW1    = (const float*)d_in[15];
    const float* mb1    = (const float*)d_in[16];
    const float* mW2    = (const float*)d_in[17];
    const float* mb2    = (const float*)d_in[18];
    const float* mW3    = (const float*)d_in[19];
    const float* mb3    = (const float*)d_in[20];
    const float* mW4    = (const float*)d_in[21];
    const float* mb4    = (const float*)d_in[22];
    float* ws  = (float*)d_ws;
    float* out = (float*)d_out;

    hipLaunchKernelGGL(pre_wr_kernel, dim3(60), dim3(256), 0, stream,
                       relf, W0, ws);
    hipLaunchKernelGGL(mid_kernel, dim3(972), dim3(512), 0, stream,
                       e2e, e2r, W1, b1, W_out, b_out, mW1, mb1, ws);
    hipLaunchKernelGGL(gf_kernel, dim3(BB), dim3(512), LDS_BYTES, stream,
                       ep, te, e2e, e2ent, e2r, b0,
                       t, eps, W1, mW1, mW2, mb2, mW3, mb3, mW4, mb4, ws, out);
}